// Round 6
// baseline (152.120 us; speedup 1.0000x reference)
//
#include <hip/hip_runtime.h>

// upfirdn2d: UP=1, DOWN=2, PAD=5, 12x12 separable sym6 kernel.
// v5: 32x64 output tile, 192 threads, bf16 LDS intermediate (9.7 KB,
//     raises blocks/CU vs 19 KB f32), NORMAL cached output stores
//     (nontemporal stores regressed r5: write-through drained into HBM
//     instead of being absorbed by write-back L2).
//     Vertical pass reads global directly (float4 sliding window,
//     <=1 task/thread before the barrier); horizontal pass reads LDS b128.

#define H_IN  256
#define W_IN  256
#define H_OUT 128
#define W_OUT 128
#define KTAP  12
#define OTR   32     // output tile rows
#define OTC   64     // output tile cols
#define VSTRU 76     // vs row stride in uints (152 bf16); mult of 4 for b128
#define NTHR  192

static __device__ __forceinline__ unsigned bf16pair(float a, float b) {
    unsigned ua = __builtin_bit_cast(unsigned, a);
    unsigned ub = __builtin_bit_cast(unsigned, b);
    ua += 0x7FFFu + ((ua >> 16) & 1u);   // RNE round to bf16
    ub += 0x7FFFu + ((ub >> 16) & 1u);
    return (ua >> 16) | (ub & 0xFFFF0000u);
}

__global__ __launch_bounds__(NTHR)
void upfirdn2d_sym6(const float* __restrict__ x,
                    const float* __restrict__ k2d,
                    float* __restrict__ out) {
    __shared__ unsigned vs[OTR * VSTRU];   // 32 x 76 uints = 9.7 KB (bf16 pairs)
    __shared__ float ks[KTAP * KTAP];
    __shared__ float wsh[KTAP];

    const int tid = threadIdx.x;

    // --- derive flipped separable taps from the 12x12 outer-product kernel
    if (tid < KTAP * KTAP) ks[tid] = k2d[tid];
    __syncthreads();
    if (tid < KTAP) {
        float tot = 0.f;
        #pragma unroll
        for (int i = 0; i < KTAP * KTAP; ++i) tot += ks[i];
        float rs = 0.f;
        #pragma unroll
        for (int q = 0; q < KTAP; ++q) rs += ks[(KTAP - 1 - tid) * KTAP + q];
        wsh[tid] = rs * rsqrtf(tot);   // w[p] = h[11-p]
    }
    __syncthreads();
    float w[KTAP];
    #pragma unroll
    for (int p = 0; p < KTAP; ++p) w[p] = wsh[p];

    const int img = blockIdx.y;            // 0..1023
    const int ti  = blockIdx.x >> 1;       // row tile 0..3 (32 out rows each)
    const int tj  = blockIdx.x & 1;        // col tile 0..1 (64 out cols each)
    const float* xim = x + (size_t)img * (H_IN * W_IN);

    const int gc0 = 128 * tj - 8;          // global col of frame word 0 (4-aligned)
    const bool edge_rows = (ti == 0) || (ti == 3);   // block-uniform

    // ---- vertical pass: 144 tasks (rg 0..3 x cg 0..35), 8 out-rows x 4 cols each
    if (tid < 144) {
        const int rg  = tid / 36;
        const int cg  = tid - rg * 36;
        const int col = gc0 + 4 * cg;
        const bool colok = (unsigned)col < (unsigned)W_IN;
        const int i0  = rg * 8;
        const int gr0 = 64 * ti + 16 * rg - 5;

        float4 acc[8];
        #pragma unroll
        for (int k = 0; k < 8; ++k) acc[k] = make_float4(0.f, 0.f, 0.f, 0.f);

        if (!edge_rows) {
            const float* rp = xim + (size_t)gr0 * W_IN + col;
            #pragma unroll
            for (int rr = 0; rr < 26; ++rr) {
                float4 v = make_float4(0.f, 0.f, 0.f, 0.f);
                if (colok) v = *reinterpret_cast<const float4*>(rp);
                rp += W_IN;
                #pragma unroll
                for (int ri = 0; ri < 8; ++ri) {
                    const int p = rr - 2 * ri;          // compile-time tap index
                    if (p >= 0 && p < KTAP) {
                        acc[ri].x = fmaf(w[p], v.x, acc[ri].x);
                        acc[ri].y = fmaf(w[p], v.y, acc[ri].y);
                        acc[ri].z = fmaf(w[p], v.z, acc[ri].z);
                        acc[ri].w = fmaf(w[p], v.w, acc[ri].w);
                    }
                }
            }
        } else {
            #pragma unroll
            for (int rr = 0; rr < 26; ++rr) {
                const int gr = gr0 + rr;
                float4 v = make_float4(0.f, 0.f, 0.f, 0.f);
                if (colok && (unsigned)gr < (unsigned)H_IN)
                    v = *reinterpret_cast<const float4*>(xim + gr * W_IN + col);
                #pragma unroll
                for (int ri = 0; ri < 8; ++ri) {
                    const int p = rr - 2 * ri;
                    if (p >= 0 && p < KTAP) {
                        acc[ri].x = fmaf(w[p], v.x, acc[ri].x);
                        acc[ri].y = fmaf(w[p], v.y, acc[ri].y);
                        acc[ri].z = fmaf(w[p], v.z, acc[ri].z);
                        acc[ri].w = fmaf(w[p], v.w, acc[ri].w);
                    }
                }
            }
        }
        // pack 4 f32 -> 2 uints (4 bf16) per row, ds_write_b64
        #pragma unroll
        for (int ri = 0; ri < 8; ++ri) {
            uint2 pk;
            pk.x = bf16pair(acc[ri].x, acc[ri].y);
            pk.y = bf16pair(acc[ri].z, acc[ri].w);
            *reinterpret_cast<uint2*>(&vs[(i0 + ri) * VSTRU + 2 * cg]) = pk;
        }
    }
    __syncthreads();

    // ---- horizontal pass: 256 tasks (i 0..31 x g 0..7), 8 outputs each
    float* oim = out + (size_t)img * (H_OUT * W_OUT);
    for (int t = tid; t < 256; t += NTHR) {
        const int i = t >> 3;
        const int g = t & 7;

        // frame f32 words 16g .. 16g+31  ==  uints i*VSTRU + 8g .. +15 (4x b128)
        float f[32];
        #pragma unroll
        for (int m = 0; m < 4; ++m) {
            uint4 u = *reinterpret_cast<const uint4*>(&vs[i * VSTRU + 8 * g + 4 * m]);
            f[8*m+0] = __builtin_bit_cast(float, u.x << 16);
            f[8*m+1] = __builtin_bit_cast(float, u.x & 0xFFFF0000u);
            f[8*m+2] = __builtin_bit_cast(float, u.y << 16);
            f[8*m+3] = __builtin_bit_cast(float, u.y & 0xFFFF0000u);
            f[8*m+4] = __builtin_bit_cast(float, u.z << 16);
            f[8*m+5] = __builtin_bit_cast(float, u.z & 0xFFFF0000u);
            f[8*m+6] = __builtin_bit_cast(float, u.w << 16);
            f[8*m+7] = __builtin_bit_cast(float, u.w & 0xFFFF0000u);
        }
        // output j = 8g+jj needs frame words 16g + 2jj+3 .. 16g + 2jj+14
        float o[8];
        #pragma unroll
        for (int jj = 0; jj < 8; ++jj) {
            float a = 0.f;
            #pragma unroll
            for (int q = 0; q < KTAP; ++q)
                a = fmaf(w[q], f[2*jj + 3 + q], a);
            o[jj] = a;
        }
        const int orow = ti * OTR + i;
        const int ocol = tj * OTC + 8 * g;
        *reinterpret_cast<float4*>(oim + orow * W_OUT + ocol)     = make_float4(o[0], o[1], o[2], o[3]);
        *reinterpret_cast<float4*>(oim + orow * W_OUT + ocol + 4) = make_float4(o[4], o[5], o[6], o[7]);
    }
}

extern "C" void kernel_launch(void* const* d_in, const int* in_sizes, int n_in,
                              void* d_out, int out_size, void* d_ws, size_t ws_size,
                              hipStream_t stream) {
    const float* x   = (const float*)d_in[0];
    const float* k2d = (const float*)d_in[1];
    float* out       = (float*)d_out;

    // 4x2 tiles of 32x64 outputs per image, 1024 images
    dim3 grid(8, 1024);
    dim3 block(NTHR);
    upfirdn2d_sym6<<<grid, block, 0, stream>>>(x, k2d, out);
}

// Round 7
// 70.951 us; speedup vs baseline: 2.1440x; 2.1440x over previous
//
#include <hip/hip_runtime.h>

// upfirdn2d: UP=1, DOWN=2, PAD=5, 12x12 separable sym6 kernel.
// v6: exactly r3's kernel (32x64 tile, 192 thr, f32 LDS VSTR=148) plus
//     nontemporal output stores. Single-variable test: r5-vs-r6 isolated
//     nt-store as -36us (bf16 LDS was the regression, now reverted).

#define H_IN  256
#define W_IN  256
#define H_OUT 128
#define W_OUT 128
#define KTAP  12
#define OTR   32    // output tile rows
#define OTC   64    // output tile cols
#define VSTR  148   // vs row stride (words)
#define NTHR  192

typedef float f32x4 __attribute__((ext_vector_type(4)));

__global__ __launch_bounds__(NTHR)
void upfirdn2d_sym6(const float* __restrict__ x,
                    const float* __restrict__ k2d,
                    float* __restrict__ out) {
    __shared__ float vs[OTR * VSTR];   // 32 x 148 x 4B = 18.5 KB
    __shared__ float ks[KTAP * KTAP];
    __shared__ float wsh[KTAP];

    const int tid = threadIdx.x;

    // --- derive flipped separable taps from the 12x12 outer-product kernel
    if (tid < KTAP * KTAP) ks[tid] = k2d[tid];
    __syncthreads();
    if (tid < KTAP) {
        float tot = 0.f;
        #pragma unroll
        for (int i = 0; i < KTAP * KTAP; ++i) tot += ks[i];
        float rs = 0.f;
        #pragma unroll
        for (int q = 0; q < KTAP; ++q) rs += ks[(KTAP - 1 - tid) * KTAP + q];
        wsh[tid] = rs * rsqrtf(tot);   // w[p] = h[11-p]
    }
    __syncthreads();
    float w[KTAP];
    #pragma unroll
    for (int p = 0; p < KTAP; ++p) w[p] = wsh[p];

    const int img = blockIdx.y;            // 0..1023
    const int ti  = blockIdx.x >> 1;       // row tile 0..3 (32 out rows each)
    const int tj  = blockIdx.x & 1;        // col tile 0..1 (64 out cols each)
    const float* xim = x + (size_t)img * (H_IN * W_IN);

    const int gc0 = 128 * tj - 8;          // global col of frame word 0 (4-aligned)
    const bool edge_rows = (ti == 0) || (ti == 3);   // block-uniform

    // ---- vertical pass: 144 tasks (rg 0..3 x cg 0..35), 8 out-rows x 4 cols each
    if (tid < 144) {
        const int rg  = tid / 36;
        const int cg  = tid - rg * 36;
        const int col = gc0 + 4 * cg;
        const bool colok = (unsigned)col < (unsigned)W_IN;
        const int i0  = rg * 8;
        const int gr0 = 64 * ti + 16 * rg - 5;

        float4 acc[8];
        #pragma unroll
        for (int k = 0; k < 8; ++k) acc[k] = make_float4(0.f, 0.f, 0.f, 0.f);

        if (!edge_rows) {
            const float* rp = xim + (size_t)gr0 * W_IN + col;
            #pragma unroll
            for (int rr = 0; rr < 26; ++rr) {
                float4 v = make_float4(0.f, 0.f, 0.f, 0.f);
                if (colok) v = *reinterpret_cast<const float4*>(rp);
                rp += W_IN;
                #pragma unroll
                for (int ri = 0; ri < 8; ++ri) {
                    const int p = rr - 2 * ri;          // compile-time tap index
                    if (p >= 0 && p < KTAP) {
                        acc[ri].x = fmaf(w[p], v.x, acc[ri].x);
                        acc[ri].y = fmaf(w[p], v.y, acc[ri].y);
                        acc[ri].z = fmaf(w[p], v.z, acc[ri].z);
                        acc[ri].w = fmaf(w[p], v.w, acc[ri].w);
                    }
                }
            }
        } else {
            #pragma unroll
            for (int rr = 0; rr < 26; ++rr) {
                const int gr = gr0 + rr;
                float4 v = make_float4(0.f, 0.f, 0.f, 0.f);
                if (colok && (unsigned)gr < (unsigned)H_IN)
                    v = *reinterpret_cast<const float4*>(xim + gr * W_IN + col);
                #pragma unroll
                for (int ri = 0; ri < 8; ++ri) {
                    const int p = rr - 2 * ri;
                    if (p >= 0 && p < KTAP) {
                        acc[ri].x = fmaf(w[p], v.x, acc[ri].x);
                        acc[ri].y = fmaf(w[p], v.y, acc[ri].y);
                        acc[ri].z = fmaf(w[p], v.z, acc[ri].z);
                        acc[ri].w = fmaf(w[p], v.w, acc[ri].w);
                    }
                }
            }
        }
        #pragma unroll
        for (int ri = 0; ri < 8; ++ri)
            *reinterpret_cast<float4*>(&vs[(i0 + ri) * VSTR + 4 * cg]) = acc[ri];
    }
    __syncthreads();

    // ---- horizontal pass: 256 tasks (i 0..31 x g 0..7), 8 outputs each
    float* oim = out + (size_t)img * (H_OUT * W_OUT);
    for (int t = tid; t < 256; t += NTHR) {
        const int i = t >> 3;
        const int g = t & 7;

        float f[32];
        #pragma unroll
        for (int m = 0; m < 8; ++m) {
            float4 v4 = *reinterpret_cast<const float4*>(&vs[i * VSTR + 16 * g + 4 * m]);
            f[4*m+0] = v4.x; f[4*m+1] = v4.y; f[4*m+2] = v4.z; f[4*m+3] = v4.w;
        }
        // output j = 8g+jj needs frame words 16g + 2jj+3 .. 16g + 2jj+14
        float o[8];
        #pragma unroll
        for (int jj = 0; jj < 8; ++jj) {
            float a = 0.f;
            #pragma unroll
            for (int q = 0; q < KTAP; ++q)
                a = fmaf(w[q], f[2*jj + 3 + q], a);
            o[jj] = a;
        }
        const int orow = ti * OTR + i;
        const int ocol = tj * OTC + 8 * g;
        f32x4 o0 = { o[0], o[1], o[2], o[3] };
        f32x4 o1 = { o[4], o[5], o[6], o[7] };
        __builtin_nontemporal_store(o0, reinterpret_cast<f32x4*>(oim + orow * W_OUT + ocol));
        __builtin_nontemporal_store(o1, reinterpret_cast<f32x4*>(oim + orow * W_OUT + ocol + 4));
    }
}

extern "C" void kernel_launch(void* const* d_in, const int* in_sizes, int n_in,
                              void* d_out, int out_size, void* d_ws, size_t ws_size,
                              hipStream_t stream) {
    const float* x   = (const float*)d_in[0];
    const float* k2d = (const float*)d_in[1];
    float* out       = (float*)d_out;

    // 4x2 tiles of 32x64 outputs per image, 1024 images
    dim3 grid(8, 1024);
    dim3 block(NTHR);
    upfirdn2d_sym6<<<grid, block, 0, stream>>>(x, k2d, out);
}

// Round 8
// 69.944 us; speedup vs baseline: 2.1749x; 1.0144x over previous
//
#include <hip/hip_runtime.h>

// upfirdn2d: UP=1, DOWN=2, PAD=5, 12x12 separable sym6 kernel.
// v7: 64x64 output tile as TWO 32-row subtiles, double-buffered LDS
//     (37.9 KB), pipelined: V(0); bar; {V(1) || H(0)}; bar; H(1).
//     V(1)'s global loads issue while H(0) computes -> vmem pipe stays
//     busy across the phase that was previously barrier-isolated.
//     f32 LDS (VSTR=148), 192 threads, nontemporal output stores.

#define H_IN  256
#define W_IN  256
#define H_OUT 128
#define W_OUT 128
#define KTAP  12
#define OTR   32    // subtile output rows
#define VSTR  148   // vs row stride (words)
#define NTHR  192

typedef float f32x4 __attribute__((ext_vector_type(4)));

__device__ __forceinline__ void vpass(const float* __restrict__ xim,
                                      float* __restrict__ buf,
                                      const float (&w)[KTAP],
                                      int tid, int b /*global out-row base*/,
                                      int gc0, bool edge) {
    if (tid < 144) {
        const int rg  = tid / 36;
        const int cg  = tid - rg * 36;
        const int col = gc0 + 4 * cg;
        const bool colok = (unsigned)col < (unsigned)W_IN;
        const int i0  = rg * 8;
        const int gr0 = 2 * (b + i0) - 5;

        float4 acc[8];
        #pragma unroll
        for (int k = 0; k < 8; ++k) acc[k] = make_float4(0.f, 0.f, 0.f, 0.f);

        if (!edge) {
            const float* rp = xim + (size_t)gr0 * W_IN + col;
            #pragma unroll
            for (int rr = 0; rr < 26; ++rr) {
                float4 v = make_float4(0.f, 0.f, 0.f, 0.f);
                if (colok) v = *reinterpret_cast<const float4*>(rp);
                rp += W_IN;
                #pragma unroll
                for (int ri = 0; ri < 8; ++ri) {
                    const int p = rr - 2 * ri;          // compile-time tap index
                    if (p >= 0 && p < KTAP) {
                        acc[ri].x = fmaf(w[p], v.x, acc[ri].x);
                        acc[ri].y = fmaf(w[p], v.y, acc[ri].y);
                        acc[ri].z = fmaf(w[p], v.z, acc[ri].z);
                        acc[ri].w = fmaf(w[p], v.w, acc[ri].w);
                    }
                }
            }
        } else {
            #pragma unroll
            for (int rr = 0; rr < 26; ++rr) {
                const int gr = gr0 + rr;
                float4 v = make_float4(0.f, 0.f, 0.f, 0.f);
                if (colok && (unsigned)gr < (unsigned)H_IN)
                    v = *reinterpret_cast<const float4*>(xim + gr * W_IN + col);
                #pragma unroll
                for (int ri = 0; ri < 8; ++ri) {
                    const int p = rr - 2 * ri;
                    if (p >= 0 && p < KTAP) {
                        acc[ri].x = fmaf(w[p], v.x, acc[ri].x);
                        acc[ri].y = fmaf(w[p], v.y, acc[ri].y);
                        acc[ri].z = fmaf(w[p], v.z, acc[ri].z);
                        acc[ri].w = fmaf(w[p], v.w, acc[ri].w);
                    }
                }
            }
        }
        #pragma unroll
        for (int ri = 0; ri < 8; ++ri)
            *reinterpret_cast<float4*>(&buf[(i0 + ri) * VSTR + 4 * cg]) = acc[ri];
    }
}

__device__ __forceinline__ void hpass(const float* __restrict__ buf,
                                      const float (&w)[KTAP],
                                      float* __restrict__ oim,
                                      int tid, int b, int ocol0) {
    for (int t = tid; t < 256; t += NTHR) {
        const int i = t >> 3;
        const int g = t & 7;

        float f[32];
        #pragma unroll
        for (int m = 0; m < 8; ++m) {
            float4 v4 = *reinterpret_cast<const float4*>(&buf[i * VSTR + 16 * g + 4 * m]);
            f[4*m+0] = v4.x; f[4*m+1] = v4.y; f[4*m+2] = v4.z; f[4*m+3] = v4.w;
        }
        float o[8];
        #pragma unroll
        for (int jj = 0; jj < 8; ++jj) {
            float a = 0.f;
            #pragma unroll
            for (int q = 0; q < KTAP; ++q)
                a = fmaf(w[q], f[2*jj + 3 + q], a);
            o[jj] = a;
        }
        f32x4 o0 = { o[0], o[1], o[2], o[3] };
        f32x4 o1 = { o[4], o[5], o[6], o[7] };
        float* dst = oim + (size_t)(b + i) * W_OUT + ocol0 + 8 * g;
        __builtin_nontemporal_store(o0, reinterpret_cast<f32x4*>(dst));
        __builtin_nontemporal_store(o1, reinterpret_cast<f32x4*>(dst + 4));
    }
}

__global__ __launch_bounds__(NTHR)
void upfirdn2d_sym6(const float* __restrict__ x,
                    const float* __restrict__ k2d,
                    float* __restrict__ out) {
    __shared__ float vs[2][OTR * VSTR];   // 2 x 32 x 148 x 4B = 37.9 KB
    __shared__ float ks[KTAP * KTAP];
    __shared__ float wsh[KTAP];

    const int tid = threadIdx.x;

    // --- derive flipped separable taps from the 12x12 outer-product kernel
    if (tid < KTAP * KTAP) ks[tid] = k2d[tid];
    __syncthreads();
    if (tid < KTAP) {
        float tot = 0.f;
        #pragma unroll
        for (int i = 0; i < KTAP * KTAP; ++i) tot += ks[i];
        float rs = 0.f;
        #pragma unroll
        for (int q = 0; q < KTAP; ++q) rs += ks[(KTAP - 1 - tid) * KTAP + q];
        wsh[tid] = rs * rsqrtf(tot);   // w[p] = h[11-p]
    }
    __syncthreads();
    float w[KTAP];
    #pragma unroll
    for (int p = 0; p < KTAP; ++p) w[p] = wsh[p];

    const int img = blockIdx.y;            // 0..1023
    const int ti  = blockIdx.x >> 1;       // row tile 0..1 (64 out rows each)
    const int tj  = blockIdx.x & 1;        // col tile 0..1 (64 out cols each)
    const float* xim = x + (size_t)img * (H_IN * W_IN);
    float* oim = out + (size_t)img * (H_OUT * W_OUT);

    const int gc0 = 128 * tj - 8;          // global col of frame word 0 (4-aligned)
    const int b0  = 64 * ti;               // subtile 0 out-row base
    const int b1  = 64 * ti + 32;          // subtile 1 out-row base
    const bool e0 = (ti == 0);             // top edge in subtile 0
    const bool e1 = (ti == 1);             // bottom edge in subtile 1
    const int ocol0 = 64 * tj;

    vpass(xim, vs[0], w, tid, b0, gc0, e0);
    __syncthreads();
    // pipelined region: V(1) loads in flight while H(0) computes
    vpass(xim, vs[1], w, tid, b1, gc0, e1);
    hpass(vs[0], w, oim, tid, b0, ocol0);
    __syncthreads();
    hpass(vs[1], w, oim, tid, b1, ocol0);
}

extern "C" void kernel_launch(void* const* d_in, const int* in_sizes, int n_in,
                              void* d_out, int out_size, void* d_ws, size_t ws_size,
                              hipStream_t stream) {
    const float* x   = (const float*)d_in[0];
    const float* k2d = (const float*)d_in[1];
    float* out       = (float*)d_out;

    // 2x2 tiles of 64x64 outputs per image, 1024 images
    dim3 grid(4, 1024);
    dim3 block(NTHR);
    upfirdn2d_sym6<<<grid, block, 0, stream>>>(x, k2d, out);
}